// Round 9
// baseline (332.860 us; speedup 1.0000x reference)
//
#include <hip/hip_runtime.h>
#include <hip/hip_bf16.h>

typedef short v8s __attribute__((ext_vector_type(8)));
typedef float v4f __attribute__((ext_vector_type(4)));

#define DD 128
#define KTOT 64
#define RANK 16

// ws layout (shorts):
//   16 half-tiles of 16384 shorts (32 KB) each: half hi = kg*2 + h  (h = rr>>2)
//     within a half: P frags at [0,8192) | Q frags at [8192,16384)
//     P/Q fragment index: (((rr&3)*4+kk)*64 + lane)*8 + j
//     lane=(q*16+c): k=kg*8+(c&7), r=2*rr+(c>>3), d=(kk*4+q)*8+j
//   W~ at [262144, 278528): ((kg*4+kk)*64 + lane)*8 + j  (c>=8 lanes are zero)
#define WOFF 262144

__device__ __forceinline__ unsigned int pk_bf16_trunc(float a, float b) {
  return __builtin_amdgcn_perm(__builtin_bit_cast(unsigned int, b),
                               __builtin_bit_cast(unsigned int, a),
                               0x07060302u);
}

__device__ __forceinline__ unsigned short bf16_rne(float x) {
  unsigned int u = __builtin_bit_cast(unsigned int, x);
  u += 0x7FFFu + ((u >> 16) & 1u);
  return (unsigned short)(u >> 16);
}

// async global->LDS, 16B per lane; LDS dest = wave-uniform base + lane*16
__device__ __forceinline__ void stage16(const unsigned short* g, unsigned short* l) {
  __builtin_amdgcn_global_load_lds(
      (const __attribute__((address_space(1))) void*)g,
      (__attribute__((address_space(3))) void*)l, 16, 0, 0);
}

// ---------------- pre-pass: swizzle weights into B-fragment layout ----------
__global__ __launch_bounds__(256)
void swizzle_weights_kernel(const float* __restrict__ Wl,
                            const float* __restrict__ P,
                            const float* __restrict__ Q,
                            unsigned short* __restrict__ ws) {
  const int tid = blockIdx.x * 256 + threadIdx.x;
  if (tid < 16384) {
    // P/Q fragments
    const int kg    = tid >> 11;
    const int rr    = (tid >> 8) & 7;
    const int kk    = (tid >> 6) & 3;
    const int lane  = tid & 63;
    const int q = lane >> 4, c = lane & 15;
    const int k = kg * 8 + (c & 7);
    const int r = rr * 2 + (c >> 3);
    const int dbase = (kk * 4 + q) * 8;
    const float* Pg = P + ((long)k * DD) * RANK + r;   // P[k][d][r]
    const float* Qg = Q + ((long)k * DD) * RANK + r;
    union { v8s v; unsigned short h[8]; } po, qo;
#pragma unroll
    for (int j = 0; j < 8; ++j) {
      po.h[j] = bf16_rne(Pg[(long)(dbase + j) * RANK]);
      qo.h[j] = bf16_rne(Qg[(long)(dbase + j) * RANK]);
    }
    // half-tile layout: hi = kg*2 + (rr>>2); local = ((rr&3)*4+kk)*64 + lane
    const long base  = (long)(kg * 2 + (rr >> 2)) * 16384;
    const long local = (long)(((rr & 3) * 4 + kk) * 64 + lane) * 8;
    *(v8s*)(ws + base + local)        = po.v;
    *(v8s*)(ws + base + 8192 + local) = qo.v;
  } else if (tid < 16384 + 2048) {
    const int t2   = tid - 16384;
    const int kg   = t2 >> 8;
    const int kk   = (t2 >> 6) & 3;
    const int lane = t2 & 63;
    const int q = lane >> 4, c = lane & 15;
    union { v8s v; unsigned short h[8]; } wo;
#pragma unroll
    for (int j = 0; j < 8; ++j) wo.h[j] = 0;
    if (c < 8) {
      const float* wrow = Wl + (long)(kg * 8 + c) * DD + (kk * 4 + q) * 8;
#pragma unroll
      for (int j = 0; j < 8; ++j) wo.h[j] = bf16_rne(wrow[j]);
    }
    *(v8s*)(ws + WOFF + (long)t2 * 8) = wo.v;
  }
}

// ---------------- main kernel: 256 blocks x 1024 threads, 512 rows/block ----
// R8 lesson: at 2 waves/SIMD, NOTHING in the schedule moves the needle
// (counted vmcnt, buffering depth, W placement all neutral; R3's traffic
// halving also neutral). Occupancy is the only live lever. R5/R7 lesson:
// launch_bounds 2nd arg w caps arch VGPR at 256/w (w=4 -> 64 -> spill).
// This round: PHYSICAL occupancy via block shape — a 1024-thread block puts
// 4 waves on every SIMD by construction (R5 proved 42% materializes), while
// w=2 keeps the VGPR cap at 128 >= the measured 108 demand -> no spill.
// 16 waves x 128 = 2048 = exact per-CU pool; 128 KB LDS = 1 block/CU;
// grid 256 = ONE round. Pipeline identical to R8: 3 x 32 KB buffers,
// depth-2 prefetch, counted vmcnt (never 0 in-loop), raw s_barrier,
// setprio around MFMA, W~ LDS-resident.
__global__ __launch_bounds__(1024, 2)
void antisym_bilinear_kernel(const float* __restrict__ x1,
                             const float* __restrict__ x2,
                             const unsigned short* __restrict__ wsw,
                             float* __restrict__ out) {
  __shared__ unsigned short lds3[3][16384];  // per buf: P [0,8192) | Q [8192,16384)
  __shared__ unsigned short wlds[16384];     // W fragments, all 8 kg

  const int b    = blockIdx.x;      // 256 blocks, 512 rows each
  const int tid  = threadIdx.x;
  const int lane = tid & 63;
  const int wave = tid >> 6;        // 0..15
  const int q    = lane >> 4;
  const int c    = lane & 15;

  const int strip0 = b * 32 + wave * 2;   // 16-row strips; 2 per wave

  // ---- prologue staging: halves 0,1 -> buf0,buf1 and W -> wlds
  // (16 waves x 2 chunks = 32 x 1 KB chunks per 32 KB image)
#pragma unroll
  for (int i = 0; i < 2; ++i) {
    const int ch = (wave * 2 + i) * 512;
    stage16(wsw + ch + lane * 8,         &lds3[0][0] + ch);
    stage16(wsw + 16384 + ch + lane * 8, &lds3[1][0] + ch);
    stage16(wsw + WOFF + ch + lane * 8,  wlds + ch);
  }

  // ---- A-fragments (persistent): Z = x1-x2, S = x1+x2, built from global f32
  v8s Zf[2][4], Sf[2][4];
#pragma unroll
  for (int t = 0; t < 2; ++t) {
    const int row = (strip0 + t) * 16 + c;       // A: m = lane&15
    const float4* p1 = (const float4*)(x1 + (long)row * DD);
    const float4* p2 = (const float4*)(x2 + (long)row * DD);
#pragma unroll
    for (int kk = 0; kk < 4; ++kk) {
      const int i0 = kk * 8 + q * 2;             // d0 = kk*32 + q*8
      float4 a0 = p1[i0], a1 = p1[i0 + 1];
      float4 b0 = p2[i0], b1 = p2[i0 + 1];
      union { v8s v; unsigned int u[4]; } z, s;
      z.u[0] = pk_bf16_trunc(a0.x - b0.x, a0.y - b0.y);
      z.u[1] = pk_bf16_trunc(a0.z - b0.z, a0.w - b0.w);
      z.u[2] = pk_bf16_trunc(a1.x - b1.x, a1.y - b1.y);
      z.u[3] = pk_bf16_trunc(a1.z - b1.z, a1.w - b1.w);
      s.u[0] = pk_bf16_trunc(a0.x + b0.x, a0.y + b0.y);
      s.u[1] = pk_bf16_trunc(a0.z + b0.z, a0.w + b0.w);
      s.u[2] = pk_bf16_trunc(a1.x + b1.x, a1.y + b1.y);
      s.u[3] = pk_bf16_trunc(a1.z + b1.z, a1.w + b1.w);
      Zf[t][kk] = z.v;
      Sf[t][kk] = s.v;
    }
  }

  asm volatile("s_waitcnt vmcnt(0)" ::: "memory");
  __builtin_amdgcn_sched_barrier(0);
  __builtin_amdgcn_s_barrier();
  __builtin_amdgcn_sched_barrier(0);

#pragma unroll
  for (int kg = 0; kg < 8; ++kg) {
    v4f acc[2];
#pragma unroll
    for (int t = 0; t < 2; ++t) acc[t] = (v4f){0.f, 0.f, 0.f, 0.f};

#pragma unroll
    for (int half = 0; half < 2; ++half) {
      const int h = kg * 2 + half;               // phase index 0..15

      // issue depth-2 prefetch: half h+2 -> buf[(h+2)%3] (read last in h-1)
      if (h < 14) {
        const unsigned short* gp = wsw + (long)(h + 2) * 16384 + lane * 8;
        unsigned short* lbuf = &lds3[(h + 2) % 3][0];
#pragma unroll
        for (int i = 0; i < 2; ++i) {
          const int ch = (wave * 2 + i) * 512;
          stage16(gp + ch, lbuf + ch);
        }
      }

      const unsigned short* lp = &lds3[h % 3][0] + lane * 8;
      __builtin_amdgcn_s_setprio(1);
#pragma unroll
      for (int rr = 0; rr < 4; ++rr) {
        v8s Pf[4], Qf[4];
#pragma unroll
        for (int kk = 0; kk < 4; ++kk) {
          const int o = (rr * 4 + kk) * 512;     // compile-time ds offsets
          Pf[kk] = *(const v8s*)(lp + o);
          Qf[kk] = *(const v8s*)(lp + 8192 + o);
        }
#pragma unroll
        for (int t = 0; t < 2; ++t) {
          v4f ap = (v4f){0.f, 0.f, 0.f, 0.f};
          v4f aq = (v4f){0.f, 0.f, 0.f, 0.f};
#pragma unroll
          for (int kk = 0; kk < 4; ++kk) {
            ap = __builtin_amdgcn_mfma_f32_16x16x32_bf16(Zf[t][kk], Pf[kk], ap, 0, 0, 0);
            aq = __builtin_amdgcn_mfma_f32_16x16x32_bf16(Sf[t][kk], Qf[kk], aq, 0, 0, 0);
          }
          acc[t] += ap * aq;
        }
      }
      __builtin_amdgcn_s_setprio(0);

      if (half == 1) {
        // linear term from LDS-resident W (one Wf live at a time)
        __builtin_amdgcn_s_setprio(1);
#pragma unroll
        for (int kk = 0; kk < 4; ++kk) {
          const v8s Wfk = *(const v8s*)(wlds + ((kg * 4 + kk) * 64 + lane) * 8);
#pragma unroll
          for (int t = 0; t < 2; ++t)
            acc[t] = __builtin_amdgcn_mfma_f32_16x16x32_bf16(Zf[t][kk], Wfk, acc[t], 0, 0, 0);
        }
        __builtin_amdgcn_s_setprio(0);

        // epilogue: fold odd-r half (cols 8..15) onto cols 0..7, store
#pragma unroll
        for (int t = 0; t < 2; ++t) {
          float v0 = acc[t][0], v1 = acc[t][1], v2 = acc[t][2], v3 = acc[t][3];
          v0 += __shfl_xor(v0, 8, 64);
          v1 += __shfl_xor(v1, 8, 64);
          v2 += __shfl_xor(v2, 8, 64);
          v3 += __shfl_xor(v3, 8, 64);
          const int row0 = (strip0 + t) * 16 + q * 4;  // C: row = quad*4 + reg
          const int cc = c & 7;
          float* op = out + (long)row0 * KTOT + kg * 8 + cc;
          if (c < 8) { op[0 * KTOT] = v0; op[1 * KTOT] = v1; }
          else       { op[2 * KTOT] = v2; op[3 * KTOT] = v3; }
        }
      }

      // counted-vmcnt phase boundary (no drain-to-0 in loop).
      // Per-wave in-flight at wait (steady, either parity):
      //   [stage h+1 (2) | stores (4) | stage h+2 (2)] = 8, oldest-2 = h+1
      //   -> vmcnt(6). h==14: [stage15 (2) | stores (4)] = 6 -> vmcnt(4).
      //   h==15: kernel end, no barrier.
      if (h < 15) {
        if (h == 14) asm volatile("s_waitcnt vmcnt(4)" ::: "memory");
        else         asm volatile("s_waitcnt vmcnt(6)" ::: "memory");
        __builtin_amdgcn_sched_barrier(0);
        __builtin_amdgcn_s_barrier();
        __builtin_amdgcn_sched_barrier(0);
      }
    }
  }
}

extern "C" void kernel_launch(void* const* d_in, const int* in_sizes, int n_in,
                              void* d_out, int out_size, void* d_ws, size_t ws_size,
                              hipStream_t stream) {
  (void)in_sizes; (void)n_in; (void)ws_size; (void)out_size;
  const float* x1 = (const float*)d_in[0];
  const float* x2 = (const float*)d_in[1];
  const float* Wl = (const float*)d_in[2];
  const float* P  = (const float*)d_in[3];
  const float* Q  = (const float*)d_in[4];
  float* out = (float*)d_out;
  unsigned short* ws = (unsigned short*)d_ws;   // needs 544 KB

  hipLaunchKernelGGL(swizzle_weights_kernel, dim3(72), dim3(256), 0, stream,
                     Wl, P, Q, ws);
  hipLaunchKernelGGL(antisym_bilinear_kernel, dim3(256), dim3(1024), 0, stream,
                     x1, x2, ws, out);
}

// Round 10
// 220.016 us; speedup vs baseline: 1.5129x; 1.5129x over previous
//
#include <hip/hip_runtime.h>
#include <hip/hip_bf16.h>

typedef short v8s __attribute__((ext_vector_type(8)));
typedef float v4f __attribute__((ext_vector_type(4)));

#define DD 128
#define KTOT 64
#define RANK 16

// ws layout (shorts):
//   32 quarter-tiles of 8192 shorts (16 KB) each: qi = kg*4 + (rr>>1)
//     within a quarter: P frags at [0,4096) | Q frags at [4096,8192)
//     P/Q fragment index: (((rr&1)*4+kk)*64 + lane)*8 + j
//     lane=(q*16+c): k=kg*8+(c&7), r=2*rr+(c>>3), d=(kk*4+q)*8+j
//   W~ at [262144, 278528): ((kg*4+kk)*64 + lane)*8 + j  (c>=8 lanes are zero)
#define WOFF 262144

__device__ __forceinline__ unsigned int pk_bf16_trunc(float a, float b) {
  return __builtin_amdgcn_perm(__builtin_bit_cast(unsigned int, b),
                               __builtin_bit_cast(unsigned int, a),
                               0x07060302u);
}

__device__ __forceinline__ unsigned short bf16_rne(float x) {
  unsigned int u = __builtin_bit_cast(unsigned int, x);
  u += 0x7FFFu + ((u >> 16) & 1u);
  return (unsigned short)(u >> 16);
}

// async global->LDS, 16B per lane; LDS dest = wave-uniform base + lane*16
__device__ __forceinline__ void stage16(const unsigned short* g, unsigned short* l) {
  __builtin_amdgcn_global_load_lds(
      (const __attribute__((address_space(1))) void*)g,
      (__attribute__((address_space(3))) void*)l, 16, 0, 0);
}

// ---------------- pre-pass: swizzle weights into B-fragment layout ----------
__global__ __launch_bounds__(256)
void swizzle_weights_kernel(const float* __restrict__ Wl,
                            const float* __restrict__ P,
                            const float* __restrict__ Q,
                            unsigned short* __restrict__ ws) {
  const int tid = blockIdx.x * 256 + threadIdx.x;
  if (tid < 16384) {
    // P/Q fragments
    const int kg    = tid >> 11;
    const int rr    = (tid >> 8) & 7;
    const int kk    = (tid >> 6) & 3;
    const int lane  = tid & 63;
    const int q = lane >> 4, c = lane & 15;
    const int k = kg * 8 + (c & 7);
    const int r = rr * 2 + (c >> 3);
    const int dbase = (kk * 4 + q) * 8;
    const float* Pg = P + ((long)k * DD) * RANK + r;   // P[k][d][r]
    const float* Qg = Q + ((long)k * DD) * RANK + r;
    union { v8s v; unsigned short h[8]; } po, qo;
#pragma unroll
    for (int j = 0; j < 8; ++j) {
      po.h[j] = bf16_rne(Pg[(long)(dbase + j) * RANK]);
      qo.h[j] = bf16_rne(Qg[(long)(dbase + j) * RANK]);
    }
    // quarter-tile layout: qi = kg*4 + (rr>>1); local = ((rr&1)*4+kk)*64 + lane
    const long base  = (long)(kg * 4 + (rr >> 1)) * 8192;
    const long local = (long)(((rr & 1) * 4 + kk) * 64 + lane) * 8;
    *(v8s*)(ws + base + local)        = po.v;
    *(v8s*)(ws + base + 4096 + local) = qo.v;
  } else if (tid < 16384 + 2048) {
    const int t2   = tid - 16384;
    const int kg   = t2 >> 8;
    const int kk   = (t2 >> 6) & 3;
    const int lane = t2 & 63;
    const int q = lane >> 4, c = lane & 15;
    union { v8s v; unsigned short h[8]; } wo;
#pragma unroll
    for (int j = 0; j < 8; ++j) wo.h[j] = 0;
    if (c < 8) {
      const float* wrow = Wl + (long)(kg * 8 + c) * DD + (kk * 4 + q) * 8;
#pragma unroll
      for (int j = 0; j < 8; ++j) wo.h[j] = bf16_rne(wrow[j]);
    }
    *(v8s*)(ws + WOFF + (long)t2 * 8) = wo.v;
  }
}

// ---------------- main kernel: 512 blocks x 512 threads, 256 rows/block -----
// R9 lesson: arch-VGPR cap = 256 / waves-per-EU implied by launch_bounds
// ((512,2)->128, (1024,2)->64, (*,4)->64), demand ~76-108 -> every declared
// 4-waves/EU config spills; and at w=2, occupancy pins to exactly 2/EU even
// with VGPR & LDS headroom — the declaration governs residency, not HW
// resources. This round: NO waves-per-EU declaration (single-arg
// launch_bounds: no VGPR cap, no residency pin) + LDS cut to 32 KB/block
// (quarter-tile streaming, 2 x 16 KB) so resource packing can put 2-3
// blocks/CU: at 76 VGPR -> 3 blocks (6 waves/SIMD); at ~128 -> 2 (4/SIMD).
// Pipeline = R6 pattern at quarter granularity: stage q(ph+1) -> compute
// q(ph) -> __syncthreads, 32 phases; Wf loaded at point of use.
__global__ __launch_bounds__(512)
void antisym_bilinear_kernel(const float* __restrict__ x1,
                             const float* __restrict__ x2,
                             const unsigned short* __restrict__ wsw,
                             float* __restrict__ out) {
  __shared__ unsigned short lds[2][8192];   // per buf: P [0,4096) | Q [4096,8192)

  const int b    = blockIdx.x;      // 512 blocks, 256 rows each
  const int tid  = threadIdx.x;
  const int lane = tid & 63;
  const int wave = tid >> 6;        // 0..7
  const int q    = lane >> 4;
  const int c    = lane & 15;

  const int strip0 = b * 16 + wave * 2;   // 16-row strips; 2 per wave

  // ---- prologue: stage quarter 0 -> buf0 (16 x 1 KB chunks, 2 per wave)
#pragma unroll
  for (int i = 0; i < 2; ++i) {
    const int ch = (wave * 2 + i) * 512;
    stage16(wsw + ch + lane * 8, &lds[0][0] + ch);
  }

  // ---- A-fragments (persistent): Z = x1-x2, S = x1+x2, built from global f32
  v8s Zf[2][4], Sf[2][4];
#pragma unroll
  for (int t = 0; t < 2; ++t) {
    const int row = (strip0 + t) * 16 + c;       // A: m = lane&15
    const float4* p1 = (const float4*)(x1 + (long)row * DD);
    const float4* p2 = (const float4*)(x2 + (long)row * DD);
#pragma unroll
    for (int kk = 0; kk < 4; ++kk) {
      const int i0 = kk * 8 + q * 2;             // d0 = kk*32 + q*8
      float4 a0 = p1[i0], a1 = p1[i0 + 1];
      float4 b0 = p2[i0], b1 = p2[i0 + 1];
      union { v8s v; unsigned int u[4]; } z, s;
      z.u[0] = pk_bf16_trunc(a0.x - b0.x, a0.y - b0.y);
      z.u[1] = pk_bf16_trunc(a0.z - b0.z, a0.w - b0.w);
      z.u[2] = pk_bf16_trunc(a1.x - b1.x, a1.y - b1.y);
      z.u[3] = pk_bf16_trunc(a1.z - b1.z, a1.w - b1.w);
      s.u[0] = pk_bf16_trunc(a0.x + b0.x, a0.y + b0.y);
      s.u[1] = pk_bf16_trunc(a0.z + b0.z, a0.w + b0.w);
      s.u[2] = pk_bf16_trunc(a1.x + b1.x, a1.y + b1.y);
      s.u[3] = pk_bf16_trunc(a1.z + b1.z, a1.w + b1.w);
      Zf[t][kk] = z.v;
      Sf[t][kk] = s.v;
    }
  }

  __syncthreads();   // drains quarter-0 staging (vmcnt) + barrier

  for (int kg = 0; kg < 8; ++kg) {
    v4f acc[2];
#pragma unroll
    for (int t = 0; t < 2; ++t) acc[t] = (v4f){0.f, 0.f, 0.f, 0.f};

#pragma unroll
    for (int qq = 0; qq < 4; ++qq) {             // ph = kg*4+qq; parity = qq&1
      const int ph = kg * 4 + qq;

      // stage quarter ph+1 -> other buf (read last in phase ph-1, barrier-safe)
      if (qq < 3 || kg < 7) {
        const unsigned short* gp = wsw + (long)(ph + 1) * 8192 + lane * 8;
        unsigned short* lb = &lds[(qq + 1) & 1][0];
#pragma unroll
        for (int i = 0; i < 2; ++i) {
          const int ch = (wave * 2 + i) * 512;
          stage16(gp + ch, lb + ch);
        }
      }

      const unsigned short* lp = &lds[qq & 1][0] + lane * 8;
      __builtin_amdgcn_s_setprio(1);
#pragma unroll
      for (int rr2 = 0; rr2 < 2; ++rr2) {
        v8s Pf[4], Qf[4];
#pragma unroll
        for (int kk = 0; kk < 4; ++kk) {
          const int o = (rr2 * 4 + kk) * 512;    // compile-time ds offsets
          Pf[kk] = *(const v8s*)(lp + o);
          Qf[kk] = *(const v8s*)(lp + 4096 + o);
        }
#pragma unroll
        for (int t = 0; t < 2; ++t) {
          v4f ap = (v4f){0.f, 0.f, 0.f, 0.f};
          v4f aq = (v4f){0.f, 0.f, 0.f, 0.f};
#pragma unroll
          for (int kk = 0; kk < 4; ++kk) {
            ap = __builtin_amdgcn_mfma_f32_16x16x32_bf16(Zf[t][kk], Pf[kk], ap, 0, 0, 0);
            aq = __builtin_amdgcn_mfma_f32_16x16x32_bf16(Sf[t][kk], Qf[kk], aq, 0, 0, 0);
          }
          acc[t] += ap * aq;   // matching (row,k,r) pairs: pure VALU
        }
      }
      __builtin_amdgcn_s_setprio(0);

      __syncthreads();   // buf[(qq+1)&1] staged+retired; buf[qq&1] readers done
    }

    // linear term: Wf loaded at point of use (short live range; L2-warm)
    __builtin_amdgcn_s_setprio(1);
#pragma unroll
    for (int kk = 0; kk < 4; ++kk) {
      const v8s Wfk = *(const v8s*)(wsw + WOFF + (((long)(kg * 4 + kk) * 64 + lane) * 8));
#pragma unroll
      for (int t = 0; t < 2; ++t)
        acc[t] = __builtin_amdgcn_mfma_f32_16x16x32_bf16(Zf[t][kk], Wfk, acc[t], 0, 0, 0);
    }
    __builtin_amdgcn_s_setprio(0);

    // epilogue: fold odd-r half (cols 8..15) onto cols 0..7, store 8 floats/row
    // (no LDS touched; next kg's first stage waits behind the next barrier)
#pragma unroll
    for (int t = 0; t < 2; ++t) {
      float v0 = acc[t][0], v1 = acc[t][1], v2 = acc[t][2], v3 = acc[t][3];
      v0 += __shfl_xor(v0, 8, 64);
      v1 += __shfl_xor(v1, 8, 64);
      v2 += __shfl_xor(v2, 8, 64);
      v3 += __shfl_xor(v3, 8, 64);
      const int row0 = (strip0 + t) * 16 + q * 4;  // C: row = quad*4 + reg
      const int cc = c & 7;
      float* op = out + (long)row0 * KTOT + kg * 8 + cc;
      if (c < 8) { op[0 * KTOT] = v0; op[1 * KTOT] = v1; }
      else       { op[2 * KTOT] = v2; op[3 * KTOT] = v3; }
    }
  }
}

extern "C" void kernel_launch(void* const* d_in, const int* in_sizes, int n_in,
                              void* d_out, int out_size, void* d_ws, size_t ws_size,
                              hipStream_t stream) {
  (void)in_sizes; (void)n_in; (void)ws_size; (void)out_size;
  const float* x1 = (const float*)d_in[0];
  const float* x2 = (const float*)d_in[1];
  const float* Wl = (const float*)d_in[2];
  const float* P  = (const float*)d_in[3];
  const float* Q  = (const float*)d_in[4];
  float* out = (float*)d_out;
  unsigned short* ws = (unsigned short*)d_ws;   // needs 544 KB

  hipLaunchKernelGGL(swizzle_weights_kernel, dim3(72), dim3(256), 0, stream,
                     Wl, P, Q, ws);
  hipLaunchKernelGGL(antisym_bilinear_kernel, dim3(512), dim3(512), 0, stream,
                     x1, x2, ws, out);
}